// Round 6
// baseline (172.595 us; speedup 1.0000x reference)
//
#include <hip/hip_runtime.h>

// GraphSage on MI355X — round 15.
//   prep  : feat fp32 -> fb bf16 + f8 fp8 e4m3 [N][128B] + w1,w2 -> w1T,w2T bf16 [n][k]
//   k1_agg: (round-14) quarter-buffer pipelined DMA gather, counted vmcnt(4), 8KB LDS.
//   g1    : ONE-SHOT staging: K=256 is tiny, so the WHOLE A-panel (64KB) and W (64KB)
//           are DMA'd into 128KB LDS up front (32 global_load_lds/thread, all in
//           flight -> pure HBM-BW fill), ONE __syncthreads drain, then 128 MFMAs
//           with zero further barriers. Replaces the 8x (sync+stage+drain) ping-pong
//           that held the round-9 form at ~50% duty (~35-40us for a ~10us transfer).
//           Per-chunk LDS layout kept verbatim (proven conflict-free: 64 lanes read
//           a contiguous 1KB line per fragment).
//   g2    : (round-14) fused layer-2, inline-asm parallel neighbor loads.

#define N_NODES 100000
#define DEG     16
#define FDIM    128
#define HDIM    128
#define B_NODES 8192

typedef __attribute__((ext_vector_type(8))) short bf16x8;
typedef __attribute__((ext_vector_type(8))) unsigned short u16x8;
typedef __attribute__((ext_vector_type(4))) float f32x4;
typedef __attribute__((ext_vector_type(2))) float f32x2;

static __device__ __forceinline__ unsigned short f2bf(float f) {
    union { float f; unsigned u; } v; v.f = f;
    unsigned r = v.u + 0x7fff + ((v.u >> 16) & 1);   // RNE
    return (unsigned short)(r >> 16);
}
static __device__ __forceinline__ float bf2f(unsigned short b) {
    union { unsigned u; float f; } v; v.u = ((unsigned)b) << 16;
    return v.f;
}

// blocks 0..6249: cast feat -> fb (bf16) + f8 (fp8). blocks 6250..6265: w1/w2 transpose.
__global__ __launch_bounds__(256)
void prep(const float* __restrict__ feat, const float* __restrict__ w1,
          const float* __restrict__ w2, unsigned short* __restrict__ fb,
          unsigned char* __restrict__ f8,
          unsigned short* __restrict__ w1T, unsigned short* __restrict__ w2T) {
    if (blockIdx.x < 6250) {
        long e = ((long)blockIdx.x * 256 + threadIdx.x) * 8;   // 6250*256*8 = 12.8M exact
        float4 v0 = *(const float4*)(feat + e);
        float4 v1 = *(const float4*)(feat + e + 4);
        u16x8 ob;
        ob[0] = f2bf(v0.x); ob[1] = f2bf(v0.y); ob[2] = f2bf(v0.z); ob[3] = f2bf(v0.w);
        ob[4] = f2bf(v1.x); ob[5] = f2bf(v1.y); ob[6] = f2bf(v1.z); ob[7] = f2bf(v1.w);
        *(u16x8*)(fb + e) = ob;
        int p0 = 0, p1 = 0;
        p0 = __builtin_amdgcn_cvt_pk_fp8_f32(v0.x, v0.y, p0, false);
        p0 = __builtin_amdgcn_cvt_pk_fp8_f32(v0.z, v0.w, p0, true);
        p1 = __builtin_amdgcn_cvt_pk_fp8_f32(v1.x, v1.y, p1, false);
        p1 = __builtin_amdgcn_cvt_pk_fp8_f32(v1.z, v1.w, p1, true);
        uint2 o8; o8.x = (unsigned)p0; o8.y = (unsigned)p1;
        *(uint2*)(f8 + e) = o8;
    } else {
        int bid = blockIdx.x - 6250;
        const float* w = (bid < 8) ? w1 : w2;
        unsigned short* wT = (bid < 8) ? w1T : w2T;
        int kb = (bid & 7) * 32;
        int n = threadIdx.x & 127, dk = threadIdx.x >> 7;
#pragma unroll
        for (int i = 0; i < 16; ++i) {
            int k = kb + dk * 16 + i;
            wT[n * 256 + k] = f2bf(w[k * 128 + n]);   // read coalesced over n
        }
    }
}

// Quarter-buffer pipelined gather. 8 nodes/block, 1 wave, no barriers.
__global__ __launch_bounds__(64)
void k1_agg(const unsigned char* __restrict__ f8, const int* __restrict__ nbr,
            unsigned short* __restrict__ agg) {
    __shared__ unsigned char L[8][1024];   // 8 KB -> 20 blocks/CU
    const int lane = threadIdx.x;
    const int node = blockIdx.x * 8 + (lane >> 3);   // 12500*8 = 100000 exact
    const int sub = lane & 7;
    const int* idx = nbr + node * DEG;
    int4 i0 = *(const int4*)(idx);
    int4 i1 = *(const int4*)(idx + 4);
    int4 i2 = *(const int4*)(idx + 8);
    int4 i3 = *(const int4*)(idx + 12);
    const int id[16] = {i0.x, i0.y, i0.z, i0.w, i1.x, i1.y, i1.z, i1.w,
                        i2.x, i2.y, i2.z, i2.w, i3.x, i3.y, i3.z, i3.w};

#define K1_ISSUE(Q, B)                                                          \
    _Pragma("unroll")                                                           \
    for (int j_ = 0; j_ < 4; ++j_) {                                            \
        const unsigned char* src_ = f8 + (long)id[(Q) * 4 + j_] * 128 + sub * 16; \
        __builtin_amdgcn_global_load_lds(                                       \
            (const __attribute__((address_space(1))) unsigned int*)src_,        \
            (__attribute__((address_space(3))) unsigned int*)                   \
                (&L[(B) * 4 + j_][lane * 16]), 16, 0, 0);                       \
    }

    f32x2 s2[8];
#pragma unroll
    for (int j = 0; j < 8; ++j) s2[j] = (f32x2){0.f, 0.f};

#define K1_CONV(B)                                                              \
    _Pragma("unroll")                                                           \
    for (int j_ = 0; j_ < 4; ++j_) {                                            \
        uint4 v = *(const uint4*)(&L[(B) * 4 + j_][lane * 16]);                 \
        s2[0] += __builtin_amdgcn_cvt_pk_f32_fp8((int)v.x, false);              \
        s2[1] += __builtin_amdgcn_cvt_pk_f32_fp8((int)v.x, true);               \
        s2[2] += __builtin_amdgcn_cvt_pk_f32_fp8((int)v.y, false);              \
        s2[3] += __builtin_amdgcn_cvt_pk_f32_fp8((int)v.y, true);               \
        s2[4] += __builtin_amdgcn_cvt_pk_f32_fp8((int)v.z, false);              \
        s2[5] += __builtin_amdgcn_cvt_pk_f32_fp8((int)v.z, true);               \
        s2[6] += __builtin_amdgcn_cvt_pk_f32_fp8((int)v.w, false);              \
        s2[7] += __builtin_amdgcn_cvt_pk_f32_fp8((int)v.w, true);               \
    }

    K1_ISSUE(0, 0);
    K1_ISSUE(1, 1);
    asm volatile("s_waitcnt vmcnt(4)" ::: "memory");
    __builtin_amdgcn_sched_barrier(0);
    K1_CONV(0);
    __builtin_amdgcn_sched_barrier(0);
    K1_ISSUE(2, 0);
    asm volatile("s_waitcnt vmcnt(4)" ::: "memory");
    __builtin_amdgcn_sched_barrier(0);
    K1_CONV(1);
    __builtin_amdgcn_sched_barrier(0);
    K1_ISSUE(3, 1);
    asm volatile("s_waitcnt vmcnt(4)" ::: "memory");
    __builtin_amdgcn_sched_barrier(0);
    K1_CONV(0);
    asm volatile("s_waitcnt vmcnt(0)" ::: "memory");
    __builtin_amdgcn_sched_barrier(0);
    K1_CONV(1);

    u16x8 o0, o1;
#pragma unroll
    for (int j = 0; j < 8; ++j) {
        o0[j] = f2bf(s2[j >> 1][j & 1] * 0.0625f);
        o1[j] = f2bf(s2[4 + (j >> 1)][j & 1] * 0.0625f);
    }
    unsigned short* dst = agg + (long)node * 128 + sub * 16;
    *(u16x8*)dst = o0;
    *(u16x8*)(dst + 8) = o1;
}

// Stage K-chunk KC (A rows + W rows, 8 KB each) into its own LDS slot. Layout and
// source mapping identical to the proven round-9 STAGE; slot index = KC (8 slots).
#define STAGE8(KC)                                                                            \
    do {                                                                                      \
        const unsigned short* s0_ = ((KC) < 4) ? (fb + (KC) * 32) : (agg + ((KC) - 4) * 32);  \
        _Pragma("unroll")                                                                     \
        for (int j_ = 0; j_ < 2; ++j_) {                                                      \
            long grow_ = row0 + (t >> 2) + j_ * 64;                                           \
            const unsigned short* ga_ = s0_ + grow_ * 128 + (t & 3) * 8;                      \
            __builtin_amdgcn_global_load_lds(                                                 \
                (const __attribute__((address_space(1))) unsigned int*)ga_,                   \
                (__attribute__((address_space(3))) unsigned int*)                             \
                    (&AsS[(KC) * 4096 + wave * 512 + j_ * 2048 + lane * 8]), 16, 0, 0);       \
            const unsigned short* gw_ = w1T + ((t >> 2) + j_ * 64) * 256 + (KC) * 32 + (t & 3) * 8; \
            __builtin_amdgcn_global_load_lds(                                                 \
                (const __attribute__((address_space(1))) unsigned int*)gw_,                   \
                (__attribute__((address_space(3))) unsigned int*)                             \
                    (&WsS[(KC) * 4096 + wave * 512 + j_ * 2048 + lane * 8]), 16, 0, 0);       \
        }                                                                                     \
    } while (0)

// GEMM: h1[N,128] = [fb | agg] @ w1T. 128 rows/block, ONE-SHOT full-K staging:
// 32 DMAs/thread (128KB LDS), one __syncthreads drain, 128 MFMAs, store. No
// double-buffer, no per-chunk barriers. 1 block/CU (LDS-limited) — latency is
// hidden by DMA depth, not TLP.
__global__ __launch_bounds__(256)
void g1(const unsigned short* __restrict__ fb, const unsigned short* __restrict__ agg,
        const unsigned short* __restrict__ w1T, unsigned short* __restrict__ h1) {
    __shared__ unsigned short AsS[8 * 4096];   // 64 KB: 8 chunks x (128 rows x 32 k)
    __shared__ unsigned short WsS[8 * 4096];   // 64 KB
    const int t = threadIdx.x, wave = t >> 6, lane = t & 63;
    const int m16 = lane & 15, quad = lane >> 4;
    const long row0 = (long)blockIdx.x * 128;

    STAGE8(0); STAGE8(1); STAGE8(2); STAGE8(3);
    STAGE8(4); STAGE8(5); STAGE8(6); STAGE8(7);
    __syncthreads();   // single vmcnt(0) drain + barrier: everything staged

    f32x4 acc[2][8] = {};
#pragma unroll
    for (int kc = 0; kc < 8; ++kc) {
        const unsigned short* Ab = &AsS[kc * 4096];
        const unsigned short* Wb = &WsS[kc * 4096];
        bf16x8 a0 = *(const bf16x8*)(Ab + (wave * 32 + m16) * 32 + quad * 8);
        bf16x8 a1 = *(const bf16x8*)(Ab + (wave * 32 + 16 + m16) * 32 + quad * 8);
#pragma unroll
        for (int nt = 0; nt < 8; ++nt) {
            bf16x8 bv = *(const bf16x8*)(Wb + (nt * 16 + m16) * 32 + quad * 8);
            acc[0][nt] = __builtin_amdgcn_mfma_f32_16x16x32_bf16(a0, bv, acc[0][nt], 0, 0, 0);
            acc[1][nt] = __builtin_amdgcn_mfma_f32_16x16x32_bf16(a1, bv, acc[1][nt], 0, 0, 0);
        }
    }

    // C layout: row = quad*4 + reg, col = nt*16 + m16
#pragma unroll
    for (int mt = 0; mt < 2; ++mt)
#pragma unroll
        for (int reg = 0; reg < 4; ++reg) {
            long grow = row0 + wave * 32 + mt * 16 + quad * 4 + reg;
            if (grow >= N_NODES) continue;
#pragma unroll
            for (int nt = 0; nt < 8; ++nt)
                h1[grow * HDIM + nt * 16 + m16] = f2bf(acc[mt][nt][reg]);
        }
}

// Layer 2 fused: 64 batch rows per 256-thread block. 128 blocks exact.
__global__ __launch_bounds__(256)
void g2_fused(const unsigned short* __restrict__ h1, const unsigned short* __restrict__ w2T,
              const int* __restrict__ nbr, const int* __restrict__ nodes,
              float* __restrict__ out) {
    __shared__ unsigned short X2[64][264];
    const int t = threadIdx.x, wave = t >> 6, lane = t & 63;
    const int m16 = lane & 15, quad = lane >> 4;
    const int b0 = blockIdx.x * 64;
    const int colb = m16 * 8;

    for (int g = 0; g < 4; ++g) {
        int Ln = wave * 16 + g * 4 + quad;
        int node = nodes[b0 + Ln];
        *(u16x8*)(&X2[Ln][colb]) = *(const u16x8*)(h1 + (long)node * HDIM + colb);
        const int* idx = nbr + node * DEG;
        int4 i0 = *(const int4*)(idx);
        int4 i1 = *(const int4*)(idx + 4);
        int4 i2 = *(const int4*)(idx + 8);
        int4 i3 = *(const int4*)(idx + 12);
        const int id[16] = {i0.x, i0.y, i0.z, i0.w, i1.x, i1.y, i1.z, i1.w,
                            i2.x, i2.y, i2.z, i2.w, i3.x, i3.y, i3.z, i3.w};

        uint4 v0, v1, v2, v3, v4, v5, v6, v7, v8, v9, v10, v11, v12, v13, v14, v15;
#define G2_LOAD(K)                                                               \
        {                                                                        \
            unsigned long long a_ =                                              \
                (unsigned long long)(h1 + (long)id[K] * HDIM + colb);            \
            asm volatile("global_load_dwordx4 %0, %1, off"                       \
                         : "=v"(v##K) : "v"(a_) : "memory");                     \
        }
        G2_LOAD(0)  G2_LOAD(1)  G2_LOAD(2)  G2_LOAD(3)
        G2_LOAD(4)  G2_LOAD(5)  G2_LOAD(6)  G2_LOAD(7)
        G2_LOAD(8)  G2_LOAD(9)  G2_LOAD(10) G2_LOAD(11)
        G2_LOAD(12) G2_LOAD(13) G2_LOAD(14) G2_LOAD(15)
#undef G2_LOAD

        float s[8] = {0.f, 0.f, 0.f, 0.f, 0.f, 0.f, 0.f, 0.f};
        asm volatile("s_waitcnt vmcnt(8)" ::: "memory");
        __builtin_amdgcn_sched_barrier(0);
#define G2_SUM(K)                                                                \
        {                                                                        \
            u16x8 w_ = __builtin_bit_cast(u16x8, v##K);                          \
            _Pragma("unroll")                                                    \
            for (int j = 0; j < 8; ++j) s[j] += bf2f(w_[j]);                     \
        }
        G2_SUM(0) G2_SUM(1) G2_SUM(2) G2_SUM(3)
        G2_SUM(4) G2_SUM(5) G2_SUM(6) G2_SUM(7)
        asm volatile("s_waitcnt vmcnt(0)" ::: "memory");
        __builtin_amdgcn_sched_barrier(0);
        G2_SUM(8)  G2_SUM(9)  G2_SUM(10) G2_SUM(11)
        G2_SUM(12) G2_SUM(13) G2_SUM(14) G2_SUM(15)
#undef G2_SUM

        u16x8 o;
#pragma unroll
        for (int j = 0; j < 8; ++j) o[j] = f2bf(s[j] * 0.0625f);
        *(u16x8*)(&X2[Ln][128 + colb]) = o;
    }
    __syncthreads();

    f32x4 acc[8] = {};
#pragma unroll
    for (int kc = 0; kc < 8; ++kc) {
        bf16x8 a = *(const bf16x8*)(&X2[wave * 16 + m16][kc * 32 + quad * 8]);
#pragma unroll
        for (int nt = 0; nt < 8; ++nt) {
            bf16x8 b = *(const bf16x8*)(w2T + (nt * 16 + m16) * 256 + kc * 32 + quad * 8);
            acc[nt] = __builtin_amdgcn_mfma_f32_16x16x32_bf16(a, b, acc[nt], 0, 0, 0);
        }
    }

#pragma unroll
    for (int nt = 0; nt < 8; ++nt)
#pragma unroll
        for (int reg = 0; reg < 4; ++reg) {
            int row = b0 + wave * 16 + quad * 4 + reg;
            out[(long)row * 128 + nt * 16 + m16] = acc[nt][reg];
        }
}

extern "C" void kernel_launch(void* const* d_in, const int* in_sizes, int n_in,
                              void* d_out, int out_size, void* d_ws, size_t ws_size,
                              hipStream_t stream) {
    const float* feat  = (const float*)d_in[0];
    const float* w1    = (const float*)d_in[1];
    const float* w2    = (const float*)d_in[2];
    const int*   nbr   = (const int*)d_in[3];
    const int*   nodes = (const int*)d_in[4];
    float* out = (float*)d_out;

    char* ws = (char*)d_ws;
    unsigned short* fb  = (unsigned short*)ws;                       // N*128 bf16 = 25.6 MB
    unsigned char*  f8  = (unsigned char*)(ws + 25600000);           // N*128 fp8  = 12.8 MB
    unsigned short* agg = (unsigned short*)(ws + 38400000);          // N*128 bf16 = 25.6 MB
    unsigned short* h1  = (unsigned short*)(ws + 64000000);          // N*128 bf16 = 25.6 MB
    unsigned short* w1T = (unsigned short*)(ws + 89600000);          // 64 KB
    unsigned short* w2T = (unsigned short*)(ws + 89665536);          // 64 KB

    prep<<<6266, 256, 0, stream>>>(feat, w1, w2, fb, f8, w1T, w2T);
    k1_agg<<<12500, 64, 0, stream>>>(f8, nbr, agg);
    g1<<<(N_NODES + 127) / 128, 256, 0, stream>>>(fb, agg, w1T, h1);
    g2_fused<<<B_NODES / 64, 256, 0, stream>>>(h1, w2T, nbr, nodes, out);
}